// Round 2
// baseline (186.371 us; speedup 1.0000x reference)
//
#include <hip/hip_runtime.h>

#define B_  2
#define S_  2048
#define E_  1024
#define H_  16
#define D_  64
#define NGLOB 2
#define NRAND 3
#define WIN 3

typedef __bf16 bf16x8 __attribute__((ext_vector_type(8)));
typedef float  f32x4  __attribute__((ext_vector_type(4)));

__device__ __forceinline__ unsigned short f2bf(float f) {
    unsigned u = __builtin_bit_cast(unsigned, f);
    unsigned r = u + 0x7FFFu + ((u >> 16) & 1u);   // RNE
    return (unsigned short)(r >> 16);
}
__device__ __forceinline__ float bf2f(unsigned short u) {
    return __builtin_bit_cast(float, (unsigned)u << 16);
}

// async global->LDS 16B DMA. LDS dest is wave-uniform base + lane*16.
__device__ __forceinline__ void g2l16(const unsigned short* g, unsigned short* l) {
    __builtin_amdgcn_global_load_lds(
        (const __attribute__((address_space(1))) unsigned*)g,
        (__attribute__((address_space(3))) unsigned*)l, 16, 0, 0);
}

// ---------------- fused fp32 -> bf16 conversion for x + 4 weights ----------------
__global__ __launch_bounds__(256)
void convert_all(const float* __restrict__ x,  const float* __restrict__ qw,
                 const float* __restrict__ kw, const float* __restrict__ vw,
                 const float* __restrict__ ow,
                 unsigned short* __restrict__ xb, unsigned short* __restrict__ wqkv,
                 unsigned short* __restrict__ wo) {
    const int XN = (B_ * S_ * E_) / 4;      // 1048576
    const int WN = (E_ * E_) / 4;           // 262144
    int i = blockIdx.x * blockDim.x + threadIdx.x;
    int r, loc;
    if (i < XN) { r = 0; loc = i; }
    else        { int j = i - XN; r = 1 + (j >> 18); loc = j & (WN - 1); }
    const float* src = r == 0 ? x : r == 1 ? qw : r == 2 ? kw : r == 3 ? vw : ow;
    float4 f = ((const float4*)src)[loc];
    ushort4 u;
    u.x = f2bf(f.x); u.y = f2bf(f.y); u.z = f2bf(f.z); u.w = f2bf(f.w);
    ushort4* dst = r == 0 ? (ushort4*)xb : r == 4 ? (ushort4*)wo
                 : (ushort4*)wqkv + (size_t)(r - 1) * WN;
    dst[loc] = u;
}

// ---------------- QKV GEMM: BK=64, XOR-swizzled LDS (known-good R0 version) -------
// (256,3): 768-block grid fully resident in ONE round (256 CU x 3) — no tail.
__global__ __launch_bounds__(256, 3)
void gemm_qkv(const unsigned short* __restrict__ A,  // [M][K] bf16
              const unsigned short* __restrict__ W,  // [N][K] bf16
              const float* __restrict__ b0, const float* __restrict__ b1,
              const float* __restrict__ b2,
              unsigned short* __restrict__ Cb, int M, int N, int K) {
    __shared__ unsigned short sA[128 * 64];   // 16 KB
    __shared__ unsigned short sB[128 * 64];   // 16 KB
    const int t = threadIdx.x;
    const int lane = t & 63;
    const int wave = t >> 6;
    const int wm = wave >> 1, wn = wave & 1;
    const int lq = lane >> 4;
    const int lr = lane & 15;
    const int bm = blockIdx.x * 128;
    const int bn = blockIdx.y * 128;

    f32x4 acc[4][4] = {};

    for (int k0 = 0; k0 < K; k0 += 64) {
        const unsigned short* Abase = A + (size_t)bm * K + k0;
        const unsigned short* Wbase = W + (size_t)bn * K + k0;
        #pragma unroll
        for (int j = 0; j < 4; ++j) {             // 1024 chunks each
            int c = j * 256 + t;
            int row = c >> 3, cc = c & 7;
            int gcol = ((cc ^ (row & 7)) << 3);   // swizzled source col
            int dst = j * 2048 + wave * 512;      // wave-uniform elem offset
            g2l16(Abase + (size_t)row * K + gcol, sA + dst);
            g2l16(Wbase + (size_t)row * K + gcol, sB + dst);
        }
        __syncthreads();

        #pragma unroll
        for (int ks = 0; ks < 2; ++ks) {
            const int sw = (((ks << 2) + lq) ^ (lr & 7)) << 3;
            bf16x8 af[4], bfr[4];
            #pragma unroll
            for (int i = 0; i < 4; ++i)
                af[i] = *(const bf16x8*)&sA[(wm * 64 + i * 16 + lr) * 64 + sw];
            #pragma unroll
            for (int j = 0; j < 4; ++j)
                bfr[j] = *(const bf16x8*)&sB[(wn * 64 + j * 16 + lr) * 64 + sw];
            #pragma unroll
            for (int i = 0; i < 4; ++i)
                #pragma unroll
                for (int j = 0; j < 4; ++j)
                    acc[i][j] = __builtin_amdgcn_mfma_f32_16x16x32_bf16(af[i], bfr[j], acc[i][j], 0, 0, 0);
        }
        __syncthreads();
    }

    #pragma unroll
    for (int i = 0; i < 4; ++i) {
        int row0 = bm + wm * 64 + i * 16 + lq * 4;
        #pragma unroll
        for (int j = 0; j < 4; ++j) {
            int col = bn + wn * 64 + j * 16 + lr;
            const float* bp = col < E_ ? b0 : (col < 2 * E_ ? b1 : b2);
            float bv = bp[col & (E_ - 1)];
            #pragma unroll
            for (int r = 0; r < 4; ++r)
                Cb[(size_t)(row0 + r) * N + col] = f2bf(acc[i][j][r] + bv);
        }
    }
}

// ---------------- O GEMM: 128x64 tile, BK=64 XOR-swizzled ----------------
__global__ __launch_bounds__(256, 2)
void gemm_o64(const unsigned short* __restrict__ A,
              const unsigned short* __restrict__ W,
              const float* __restrict__ bias,
              float* __restrict__ Cf, int M, int N, int K) {
    __shared__ unsigned short sA[128 * 64];   // 16 KB
    __shared__ unsigned short sB[64 * 64];    // 8 KB
    const int t = threadIdx.x;
    const int lane = t & 63;
    const int wave = t >> 6;
    const int lq = lane >> 4;
    const int lr = lane & 15;
    const int bm = blockIdx.x * 128;
    const int bn = blockIdx.y * 64;

    f32x4 acc[2][4] = {};

    for (int k0 = 0; k0 < K; k0 += 64) {
        const unsigned short* Abase = A + (size_t)bm * K + k0;
        const unsigned short* Wbase = W + (size_t)bn * K + k0;
        #pragma unroll
        for (int j = 0; j < 4; ++j) {           // A: 1024 chunks
            int c = j * 256 + t;
            int row = c >> 3, cc = c & 7;
            int gcol = ((cc ^ (row & 7)) << 3);
            int dst = j * 2048 + wave * 512;
            g2l16(Abase + (size_t)row * K + gcol, sA + dst);
        }
        #pragma unroll
        for (int j = 0; j < 2; ++j) {           // B: 512 chunks
            int c = j * 256 + t;
            int row = c >> 3, cc = c & 7;
            int gcol = ((cc ^ (row & 7)) << 3);
            int dst = j * 2048 + wave * 512;
            g2l16(Wbase + (size_t)row * K + gcol, sB + dst);
        }
        __syncthreads();

        #pragma unroll
        for (int ks = 0; ks < 2; ++ks) {
            const int sw = (((ks << 2) + lq) ^ (lr & 7)) << 3;
            bf16x8 af[2], bfr[4];
            #pragma unroll
            for (int i = 0; i < 2; ++i)
                af[i] = *(const bf16x8*)&sA[(wave * 32 + i * 16 + lr) * 64 + sw];
            #pragma unroll
            for (int j = 0; j < 4; ++j)
                bfr[j] = *(const bf16x8*)&sB[(j * 16 + lr) * 64 + sw];
            #pragma unroll
            for (int i = 0; i < 2; ++i)
                #pragma unroll
                for (int j = 0; j < 4; ++j)
                    acc[i][j] = __builtin_amdgcn_mfma_f32_16x16x32_bf16(af[i], bfr[j], acc[i][j], 0, 0, 0);
        }
        __syncthreads();
    }

    #pragma unroll
    for (int i = 0; i < 2; ++i) {
        int row0 = bm + wave * 32 + i * 16 + lq * 4;
        #pragma unroll
        for (int j = 0; j < 4; ++j) {
            int col = bn + j * 16 + lr;
            float bv = bias[col];
            #pragma unroll
            for (int r = 0; r < 4; ++r)
                Cf[(size_t)(row0 + r) * N + col] = acc[i][j][r] + bv;
        }
    }
}

// ---------------- fused: global rows (self-contained) + sparse rows --------------
// R2: blocks [0,64) each own one (b,i,h) global tuple end-to-end: QK over all 2048
// keys, block softmax, PV, bf16 write. Replaces {512 score blocks + gattn_pv(512,
// 8x-redundant softmax, atomics) + gattn_fin + gsc/gacc round-trip}. Blocks
// [64,1088) = sparse rows, one wave per row (unchanged from R0).
__global__ __launch_bounds__(256)
void attn_fused(const unsigned short* __restrict__ qkv,
                const int* __restrict__ rnd,
                unsigned short* __restrict__ attn) {
    const int NB = B_ * (S_ - 2);     // 4092
    int t = threadIdx.x;

    if (blockIdx.x < 64) {
        // ---- one global tuple per block ----
        int tup = blockIdx.x;
        int b = tup >> 5, i = (tup >> 4) & 1, h = tup & 15;
        int w = t >> 6, l = t & 63;
        __shared__ float qs[D_];
        __shared__ float ps[S_];       // 8 KB probs
        __shared__ float red[4];
        __shared__ float ov[4][D_];
        if (t < D_) qs[t] = bf2f(qkv[(size_t)(b * S_ + i) * 3072 + h * D_ + t]);
        __syncthreads();

        // scores: thread handles keys t + 256*kk
        float vals[8];
        float m = -1e30f;
        #pragma unroll
        for (int kk = 0; kk < 8; ++kk) {
            int c = kk * 256 + t;
            const bf16x8* kp = (const bf16x8*)(qkv + (size_t)(b * S_ + c) * 3072 + E_ + h * D_);
            float s = 0.f;
            #pragma unroll
            for (int u = 0; u < 8; ++u) {
                bf16x8 kv = kp[u];
                #pragma unroll
                for (int j = 0; j < 8; ++j) s += qs[u * 8 + j] * (float)kv[j];
            }
            vals[kk] = s * 0.125f;
            m = fmaxf(m, vals[kk]);
        }
        #pragma unroll
        for (int o = 32; o; o >>= 1) m = fmaxf(m, __shfl_down(m, o));
        if (l == 0) red[w] = m;
        __syncthreads();
        m = fmaxf(fmaxf(red[0], red[1]), fmaxf(red[2], red[3]));
        __syncthreads();
        float sum = 0.f;
        #pragma unroll
        for (int kk = 0; kk < 8; ++kk) { float e = __expf(vals[kk] - m); vals[kk] = e; sum += e; }
        #pragma unroll
        for (int o = 32; o; o >>= 1) sum += __shfl_down(sum, o);
        if (l == 0) red[w] = sum;
        __syncthreads();
        float inv = 1.f / (red[0] + red[1] + red[2] + red[3]);
        #pragma unroll
        for (int kk = 0; kk < 8; ++kk) ps[kk * 256 + t] = vals[kk] * inv;
        __syncthreads();

        // PV: wave w covers keys [w*512, w*512+512); lane l owns dim d=l
        const unsigned short* vbase = qkv + (size_t)(b * S_ + w * 512) * 3072 + 2 * E_ + h * D_ + l;
        const float* pw = ps + w * 512;
        float acc = 0.f;
        #pragma unroll 8
        for (int k = 0; k < 512; ++k)
            acc += pw[k] * bf2f(vbase[(size_t)k * 3072]);
        ov[w][l] = acc;
        __syncthreads();
        if (w == 0)
            attn[(size_t)(b * S_ + i) * E_ + h * D_ + l] =
                f2bf(ov[0][l] + ov[1][l] + ov[2][l] + ov[3][l]);
        return;
    }

    // ---- sparse rows: one wave per row ----
    int bb = blockIdx.x - 64;                         // [0,1024)
    int bidx = (bb & 7) * 128 + (bb >> 3);            // XCD swizzle
    int w = t >> 6, l = t & 63;
    int row = bidx * 4 + w;
    bool valid = row < NB;
    int b = row / (S_ - 2);
    int i = row % (S_ - 2) + 2;
    if (!valid) { b = 0; i = 2; }

    __shared__ int   cols_s[4][12];
    __shared__ int   ncol_sh[4];
    __shared__ float pr_s[4][16 * 13 + 3];

    const bf16x8* qp = (const bf16x8*)(qkv + (size_t)(b * S_ + i) * 3072);
    bf16x8 q0 = qp[l * 2], q1 = qp[l * 2 + 1];
    float qreg[16];
    #pragma unroll
    for (int j = 0; j < 8; ++j) { qreg[j] = (float)q0[j]; qreg[8 + j] = (float)q1[j]; }

    if (l == 0) {
        int* cols = cols_s[w];
        int n = 0;
        cols[n++] = 0; cols[n++] = 1;
        int lo = i - WIN; if (lo < NGLOB) lo = NGLOB;
        int hi = i + WIN; if (hi > S_ - 1) hi = S_ - 1;
        for (int j = lo; j <= hi; ++j) cols[n++] = j;
        for (int r = 0; r < NRAND; ++r) {
            int c = rnd[i * NRAND + r];
            bool dup = false;
            for (int q = 0; q < n; ++q) dup = dup || (cols[q] == c);
            if (!dup) cols[n++] = c;
        }
        ncol_sh[w] = n;
        for (int q = n; q < 12; ++q) cols[q] = 0;
    }
    __syncthreads();
    const int n = ncol_sh[w];
    const int h4 = l >> 2;

    float sco[12];
    #pragma unroll
    for (int c = 0; c < 12; ++c) {
        const bf16x8* kp = (const bf16x8*)(qkv + (size_t)(b * S_ + cols_s[w][c]) * 3072 + E_);
        bf16x8 k0 = kp[l * 2], k1 = kp[l * 2 + 1];
        float s = 0.f;
        #pragma unroll
        for (int j = 0; j < 8; ++j) s += qreg[j] * (float)k0[j] + qreg[8 + j] * (float)k1[j];
        s += __shfl_xor(s, 1);
        s += __shfl_xor(s, 2);
        sco[c] = (c < n) ? s * 0.125f : -1e30f;
    }

    if ((l & 3) == 0) {
        float m = -1e30f;
        #pragma unroll
        for (int c = 0; c < 12; ++c) m = fmaxf(m, sco[c]);
        float sum = 0.f;
        #pragma unroll
        for (int c = 0; c < 12; ++c) { float e = __expf(sco[c] - m); sco[c] = e; sum += e; }
        float inv = 1.f / sum;
        #pragma unroll
        for (int c = 0; c < 12; ++c) pr_s[w][h4 * 13 + c] = sco[c] * inv;
    }
    __syncthreads();

    float o[16] = {};
    #pragma unroll
    for (int c = 0; c < 12; ++c) {
        float p = pr_s[w][h4 * 13 + c];
        const bf16x8* vp = (const bf16x8*)(qkv + (size_t)(b * S_ + cols_s[w][c]) * 3072 + 2 * E_);
        bf16x8 v0 = vp[l * 2], v1 = vp[l * 2 + 1];
        #pragma unroll
        for (int j = 0; j < 8; ++j) { o[j] += p * (float)v0[j]; o[8 + j] += p * (float)v1[j]; }
    }

    if (valid) {
        ushort4 u0, u1, u2, u3;
        u0.x = f2bf(o[0]);  u0.y = f2bf(o[1]);  u0.z = f2bf(o[2]);  u0.w = f2bf(o[3]);
        u1.x = f2bf(o[4]);  u1.y = f2bf(o[5]);  u1.z = f2bf(o[6]);  u1.w = f2bf(o[7]);
        u2.x = f2bf(o[8]);  u2.y = f2bf(o[9]);  u2.z = f2bf(o[10]); u2.w = f2bf(o[11]);
        u3.x = f2bf(o[12]); u3.y = f2bf(o[13]); u3.z = f2bf(o[14]); u3.w = f2bf(o[15]);
        ushort4* op = (ushort4*)(attn + (size_t)(b * S_ + i) * E_ + l * 16);
        op[0] = u0; op[1] = u1; op[2] = u2; op[3] = u3;
    }
}

extern "C" void kernel_launch(void* const* d_in, const int* in_sizes, int n_in,
                              void* d_out, int out_size, void* d_ws, size_t ws_size,
                              hipStream_t stream) {
    const float* x   = (const float*)d_in[0];
    const int*   rnd = (const int*)d_in[1];
    const float* qw  = (const float*)d_in[2];
    const float* qb  = (const float*)d_in[3];
    const float* kw  = (const float*)d_in[4];
    const float* kb  = (const float*)d_in[5];
    const float* vw  = (const float*)d_in[6];
    const float* vb  = (const float*)d_in[7];
    const float* ow  = (const float*)d_in[8];
    const float* ob  = (const float*)d_in[9];
    float* out = (float*)d_out;

    char* ws = (char*)d_ws;
    unsigned short* xb    = (unsigned short*)(ws);                       // 8 MB (dead after QKV GEMM)
    unsigned short* wqkv  = (unsigned short*)(ws + 8388608);             // 6 MB
    unsigned short* wo    = (unsigned short*)(ws + 14680064);            // 2 MB
    unsigned short* qkv   = (unsigned short*)(ws + 16777216);            // 24 MB
    unsigned short* attn  = (unsigned short*)(ws + 41943040);            // 8 MB

    const int M = B_ * S_;   // 4096

    {
        int total4 = (M * E_ + 4 * E_ * E_) / 4;
        convert_all<<<total4 / 256, 256, 0, stream>>>(x, qw, kw, vw, ow, xb, wqkv, wo);
    }

    // QKV GEMM: [4096][3072] bf16, BK=64 swizzled, fully-resident grid
    {
        dim3 grid(M / 128, 3 * E_ / 128);
        gemm_qkv<<<grid, 256, 0, stream>>>(xb, wqkv, qb, kb, vb, qkv, M, 3 * E_, E_);
    }

    // global rows (self-contained, 64 blocks) + sparse rows (1024 blocks), one dispatch
    attn_fused<<<64 + 1024, 256, 0, stream>>>(qkv, rnd, attn);

    // O GEMM -> fp32 out (BK=64 swizzled)
    {
        dim3 grid(M / 128, E_ / 64);
        gemm_o64<<<grid, 256, 0, stream>>>(attn, wo, ob, out, M, E_, E_);
    }
}

// Round 3
// 185.595 us; speedup vs baseline: 1.0042x; 1.0042x over previous
//
#include <hip/hip_runtime.h>

#define B_  2
#define S_  2048
#define E_  1024
#define H_  16
#define D_  64
#define NGLOB 2
#define NRAND 3
#define WIN 3

typedef __bf16 bf16x8 __attribute__((ext_vector_type(8)));
typedef float  f32x4  __attribute__((ext_vector_type(4)));

__device__ __forceinline__ unsigned short f2bf(float f) {
    unsigned u = __builtin_bit_cast(unsigned, f);
    unsigned r = u + 0x7FFFu + ((u >> 16) & 1u);   // RNE
    return (unsigned short)(r >> 16);
}
__device__ __forceinline__ float bf2f(unsigned short u) {
    return __builtin_bit_cast(float, (unsigned)u << 16);
}

// async global->LDS 16B DMA. LDS dest is wave-uniform base + lane*16.
__device__ __forceinline__ void g2l16(const unsigned short* g, unsigned short* l) {
    __builtin_amdgcn_global_load_lds(
        (const __attribute__((address_space(1))) unsigned*)g,
        (__attribute__((address_space(3))) unsigned*)l, 16, 0, 0);
}

// ---------------- fused fp32 -> bf16 conversion for x + 4 weights ----------------
__global__ __launch_bounds__(256)
void convert_all(const float* __restrict__ x,  const float* __restrict__ qw,
                 const float* __restrict__ kw, const float* __restrict__ vw,
                 const float* __restrict__ ow,
                 unsigned short* __restrict__ xb, unsigned short* __restrict__ wqkv,
                 unsigned short* __restrict__ wo) {
    const int XN = (B_ * S_ * E_) / 4;      // 1048576
    const int WN = (E_ * E_) / 4;           // 262144
    int i = blockIdx.x * blockDim.x + threadIdx.x;
    int r, loc;
    if (i < XN) { r = 0; loc = i; }
    else        { int j = i - XN; r = 1 + (j >> 18); loc = j & (WN - 1); }
    const float* src = r == 0 ? x : r == 1 ? qw : r == 2 ? kw : r == 3 ? vw : ow;
    float4 f = ((const float4*)src)[loc];
    ushort4 u;
    u.x = f2bf(f.x); u.y = f2bf(f.y); u.z = f2bf(f.z); u.w = f2bf(f.w);
    ushort4* dst = r == 0 ? (ushort4*)xb : r == 4 ? (ushort4*)wo
                 : (ushort4*)wqkv + (size_t)(r - 1) * WN;
    dst[loc] = u;
}

// ---------------- QKV GEMM: BK=64, XOR-swizzled LDS (known-good R0 version) -------
// (256,3): 768-block grid fully resident in ONE round (256 CU x 3) — no tail.
__global__ __launch_bounds__(256, 3)
void gemm_qkv(const unsigned short* __restrict__ A,  // [M][K] bf16
              const unsigned short* __restrict__ W,  // [N][K] bf16
              const float* __restrict__ b0, const float* __restrict__ b1,
              const float* __restrict__ b2,
              unsigned short* __restrict__ Cb, int M, int N, int K) {
    __shared__ unsigned short sA[128 * 64];   // 16 KB
    __shared__ unsigned short sB[128 * 64];   // 16 KB
    const int t = threadIdx.x;
    const int lane = t & 63;
    const int wave = t >> 6;
    const int wm = wave >> 1, wn = wave & 1;
    const int lq = lane >> 4;
    const int lr = lane & 15;
    const int bm = blockIdx.x * 128;
    const int bn = blockIdx.y * 128;

    f32x4 acc[4][4] = {};

    for (int k0 = 0; k0 < K; k0 += 64) {
        const unsigned short* Abase = A + (size_t)bm * K + k0;
        const unsigned short* Wbase = W + (size_t)bn * K + k0;
        #pragma unroll
        for (int j = 0; j < 4; ++j) {             // 1024 chunks each
            int c = j * 256 + t;
            int row = c >> 3, cc = c & 7;
            int gcol = ((cc ^ (row & 7)) << 3);   // swizzled source col
            int dst = j * 2048 + wave * 512;      // wave-uniform elem offset
            g2l16(Abase + (size_t)row * K + gcol, sA + dst);
            g2l16(Wbase + (size_t)row * K + gcol, sB + dst);
        }
        __syncthreads();

        #pragma unroll
        for (int ks = 0; ks < 2; ++ks) {
            const int sw = (((ks << 2) + lq) ^ (lr & 7)) << 3;
            bf16x8 af[4], bfr[4];
            #pragma unroll
            for (int i = 0; i < 4; ++i)
                af[i] = *(const bf16x8*)&sA[(wm * 64 + i * 16 + lr) * 64 + sw];
            #pragma unroll
            for (int j = 0; j < 4; ++j)
                bfr[j] = *(const bf16x8*)&sB[(wn * 64 + j * 16 + lr) * 64 + sw];
            #pragma unroll
            for (int i = 0; i < 4; ++i)
                #pragma unroll
                for (int j = 0; j < 4; ++j)
                    acc[i][j] = __builtin_amdgcn_mfma_f32_16x16x32_bf16(af[i], bfr[j], acc[i][j], 0, 0, 0);
        }
        __syncthreads();
    }

    #pragma unroll
    for (int i = 0; i < 4; ++i) {
        int row0 = bm + wm * 64 + i * 16 + lq * 4;
        #pragma unroll
        for (int j = 0; j < 4; ++j) {
            int col = bn + wn * 64 + j * 16 + lr;
            const float* bp = col < E_ ? b0 : (col < 2 * E_ ? b1 : b2);
            float bv = bp[col & (E_ - 1)];
            #pragma unroll
            for (int r = 0; r < 4; ++r)
                Cb[(size_t)(row0 + r) * N + col] = f2bf(acc[i][j][r] + bv);
        }
    }
}

// ---------------- O GEMM: 128x64 tile, BK=64 XOR-swizzled ----------------
__global__ __launch_bounds__(256, 2)
void gemm_o64(const unsigned short* __restrict__ A,
              const unsigned short* __restrict__ W,
              const float* __restrict__ bias,
              float* __restrict__ Cf, int M, int N, int K) {
    __shared__ unsigned short sA[128 * 64];   // 16 KB
    __shared__ unsigned short sB[64 * 64];    // 8 KB
    const int t = threadIdx.x;
    const int lane = t & 63;
    const int wave = t >> 6;
    const int lq = lane >> 4;
    const int lr = lane & 15;
    const int bm = blockIdx.x * 128;
    const int bn = blockIdx.y * 64;

    f32x4 acc[2][4] = {};

    for (int k0 = 0; k0 < K; k0 += 64) {
        const unsigned short* Abase = A + (size_t)bm * K + k0;
        const unsigned short* Wbase = W + (size_t)bn * K + k0;
        #pragma unroll
        for (int j = 0; j < 4; ++j) {           // A: 1024 chunks
            int c = j * 256 + t;
            int row = c >> 3, cc = c & 7;
            int gcol = ((cc ^ (row & 7)) << 3);
            int dst = j * 2048 + wave * 512;
            g2l16(Abase + (size_t)row * K + gcol, sA + dst);
        }
        #pragma unroll
        for (int j = 0; j < 2; ++j) {           // B: 512 chunks
            int c = j * 256 + t;
            int row = c >> 3, cc = c & 7;
            int gcol = ((cc ^ (row & 7)) << 3);
            int dst = j * 2048 + wave * 512;
            g2l16(Wbase + (size_t)row * K + gcol, sB + dst);
        }
        __syncthreads();

        #pragma unroll
        for (int ks = 0; ks < 2; ++ks) {
            const int sw = (((ks << 2) + lq) ^ (lr & 7)) << 3;
            bf16x8 af[2], bfr[4];
            #pragma unroll
            for (int i = 0; i < 2; ++i)
                af[i] = *(const bf16x8*)&sA[(wave * 32 + i * 16 + lr) * 64 + sw];
            #pragma unroll
            for (int j = 0; j < 4; ++j)
                bfr[j] = *(const bf16x8*)&sB[(j * 16 + lr) * 64 + sw];
            #pragma unroll
            for (int i = 0; i < 2; ++i)
                #pragma unroll
                for (int j = 0; j < 4; ++j)
                    acc[i][j] = __builtin_amdgcn_mfma_f32_16x16x32_bf16(af[i], bfr[j], acc[i][j], 0, 0, 0);
        }
        __syncthreads();
    }

    #pragma unroll
    for (int i = 0; i < 2; ++i) {
        int row0 = bm + wave * 32 + i * 16 + lq * 4;
        #pragma unroll
        for (int j = 0; j < 4; ++j) {
            int col = bn + j * 16 + lr;
            float bv = bias[col];
            #pragma unroll
            for (int r = 0; r < 4; ++r)
                Cf[(size_t)(row0 + r) * N + col] = acc[i][j][r] + bv;
        }
    }
}

// ---------------- fused: global chunks (512-parallel) + sparse rows --------------
// R3: blocks [0,512) = (tuple x key-chunk) global attention. Each block recomputes
// ALL 2048 scores for its tuple (block-local softmax -> no cross-block dependency,
// one dispatch), then PV over only its 256-key chunk, writing a partial sum to
// gaccp[tup][seg][64] (no atomics, no zeroing). Fixes R2's 64-block tail
// (8.8% occupancy, 53.8us): global path now as wide as the sparse path.
// Blocks [512,1536) = sparse rows, one wave per row (unchanged).
__global__ __launch_bounds__(256)
void attn_fused(const unsigned short* __restrict__ qkv,
                const int* __restrict__ rnd,
                float* __restrict__ gaccp,
                unsigned short* __restrict__ attn) {
    const int NB = B_ * (S_ - 2);     // 4092
    int t = threadIdx.x;

    if (blockIdx.x < 512) {
        // ---- one (tuple, key-chunk) per block ----
        int tup = blockIdx.x >> 3, seg = blockIdx.x & 7;
        int b = tup >> 5, i = (tup >> 4) & 1, h = tup & 15;
        int w = t >> 6, l = t & 63;
        __shared__ float qs[D_];
        __shared__ float pc[256];
        __shared__ float red[4];
        __shared__ float ov[4][D_];
        if (t < D_) qs[t] = bf2f(qkv[(size_t)(b * S_ + i) * 3072 + h * D_ + t]);
        __syncthreads();

        // all 2048 scores (8 keys/thread) for block-local softmax
        float vals[8];
        float m = -1e30f;
        #pragma unroll
        for (int kk = 0; kk < 8; ++kk) {
            int c = kk * 256 + t;
            const bf16x8* kp = (const bf16x8*)(qkv + (size_t)(b * S_ + c) * 3072 + E_ + h * D_);
            float s = 0.f;
            #pragma unroll
            for (int u = 0; u < 8; ++u) {
                bf16x8 kv = kp[u];
                #pragma unroll
                for (int j = 0; j < 8; ++j) s += qs[u * 8 + j] * (float)kv[j];
            }
            vals[kk] = s * 0.125f;
            m = fmaxf(m, vals[kk]);
        }
        #pragma unroll
        for (int o = 32; o; o >>= 1) m = fmaxf(m, __shfl_down(m, o));
        if (l == 0) red[w] = m;
        __syncthreads();
        m = fmaxf(fmaxf(red[0], red[1]), fmaxf(red[2], red[3]));
        __syncthreads();
        float sum = 0.f;
        #pragma unroll
        for (int kk = 0; kk < 8; ++kk) { float e = __expf(vals[kk] - m); vals[kk] = e; sum += e; }
        #pragma unroll
        for (int o = 32; o; o >>= 1) sum += __shfl_down(sum, o);
        if (l == 0) red[w] = sum;
        __syncthreads();
        float inv = 1.f / (red[0] + red[1] + red[2] + red[3]);
        pc[t] = vals[seg] * inv;          // prob of key seg*256 + t
        __syncthreads();

        // PV over this chunk: wave w covers keys [seg*256+w*64, +64); lane l = dim
        const unsigned short* vbase =
            qkv + (size_t)(b * S_ + seg * 256 + w * 64) * 3072 + 2 * E_ + h * D_ + l;
        const float* pw = pc + w * 64;
        float acc = 0.f;
        #pragma unroll 8
        for (int k = 0; k < 64; ++k)
            acc += pw[k] * bf2f(vbase[(size_t)k * 3072]);
        ov[w][l] = acc;
        __syncthreads();
        if (w == 0)
            gaccp[((size_t)tup * 8 + seg) * D_ + l] =
                ov[0][l] + ov[1][l] + ov[2][l] + ov[3][l];
        return;
    }

    // ---- sparse rows: one wave per row ----
    int bb = blockIdx.x - 512;                        // [0,1024)
    int bidx = (bb & 7) * 128 + (bb >> 3);            // XCD swizzle
    int w = t >> 6, l = t & 63;
    int row = bidx * 4 + w;
    bool valid = row < NB;
    int b = row / (S_ - 2);
    int i = row % (S_ - 2) + 2;
    if (!valid) { b = 0; i = 2; }

    __shared__ int   cols_s[4][12];
    __shared__ int   ncol_sh[4];
    __shared__ float pr_s[4][16 * 13 + 3];

    const bf16x8* qp = (const bf16x8*)(qkv + (size_t)(b * S_ + i) * 3072);
    bf16x8 q0 = qp[l * 2], q1 = qp[l * 2 + 1];
    float qreg[16];
    #pragma unroll
    for (int j = 0; j < 8; ++j) { qreg[j] = (float)q0[j]; qreg[8 + j] = (float)q1[j]; }

    if (l == 0) {
        int* cols = cols_s[w];
        int n = 0;
        cols[n++] = 0; cols[n++] = 1;
        int lo = i - WIN; if (lo < NGLOB) lo = NGLOB;
        int hi = i + WIN; if (hi > S_ - 1) hi = S_ - 1;
        for (int j = lo; j <= hi; ++j) cols[n++] = j;
        for (int r = 0; r < NRAND; ++r) {
            int c = rnd[i * NRAND + r];
            bool dup = false;
            for (int q = 0; q < n; ++q) dup = dup || (cols[q] == c);
            if (!dup) cols[n++] = c;
        }
        ncol_sh[w] = n;
        for (int q = n; q < 12; ++q) cols[q] = 0;
    }
    __syncthreads();
    const int n = ncol_sh[w];
    const int h4 = l >> 2;

    float sco[12];
    #pragma unroll
    for (int c = 0; c < 12; ++c) {
        const bf16x8* kp = (const bf16x8*)(qkv + (size_t)(b * S_ + cols_s[w][c]) * 3072 + E_);
        bf16x8 k0 = kp[l * 2], k1 = kp[l * 2 + 1];
        float s = 0.f;
        #pragma unroll
        for (int j = 0; j < 8; ++j) s += qreg[j] * (float)k0[j] + qreg[8 + j] * (float)k1[j];
        s += __shfl_xor(s, 1);
        s += __shfl_xor(s, 2);
        sco[c] = (c < n) ? s * 0.125f : -1e30f;
    }

    if ((l & 3) == 0) {
        float m = -1e30f;
        #pragma unroll
        for (int c = 0; c < 12; ++c) m = fmaxf(m, sco[c]);
        float sum = 0.f;
        #pragma unroll
        for (int c = 0; c < 12; ++c) { float e = __expf(sco[c] - m); sco[c] = e; sum += e; }
        float inv = 1.f / sum;
        #pragma unroll
        for (int c = 0; c < 12; ++c) pr_s[w][h4 * 13 + c] = sco[c] * inv;
    }
    __syncthreads();

    float o[16] = {};
    #pragma unroll
    for (int c = 0; c < 12; ++c) {
        float p = pr_s[w][h4 * 13 + c];
        const bf16x8* vp = (const bf16x8*)(qkv + (size_t)(b * S_ + cols_s[w][c]) * 3072 + 2 * E_);
        bf16x8 v0 = vp[l * 2], v1 = vp[l * 2 + 1];
        #pragma unroll
        for (int j = 0; j < 8; ++j) { o[j] += p * (float)v0[j]; o[8 + j] += p * (float)v1[j]; }
    }

    if (valid) {
        ushort4 u0, u1, u2, u3;
        u0.x = f2bf(o[0]);  u0.y = f2bf(o[1]);  u0.z = f2bf(o[2]);  u0.w = f2bf(o[3]);
        u1.x = f2bf(o[4]);  u1.y = f2bf(o[5]);  u1.z = f2bf(o[6]);  u1.w = f2bf(o[7]);
        u2.x = f2bf(o[8]);  u2.y = f2bf(o[9]);  u2.z = f2bf(o[10]); u2.w = f2bf(o[11]);
        u3.x = f2bf(o[12]); u3.y = f2bf(o[13]); u3.z = f2bf(o[14]); u3.w = f2bf(o[15]);
        ushort4* op = (ushort4*)(attn + (size_t)(b * S_ + i) * E_ + l * 16);
        op[0] = u0; op[1] = u1; op[2] = u2; op[3] = u3;
    }
}

// sum the 8 per-chunk partials, write bf16 global rows
__global__ __launch_bounds__(256)
void gattn_fin(const float* __restrict__ gaccp, unsigned short* __restrict__ attn) {
    int gid = blockIdx.x * 256 + threadIdx.x;   // 4096
    int tup = gid >> 6, d = gid & 63;
    int b = tup >> 5, i = (tup >> 4) & 1, h = tup & 15;
    float s = 0.f;
    #pragma unroll
    for (int seg = 0; seg < 8; ++seg) s += gaccp[((size_t)tup * 8 + seg) * D_ + d];
    attn[(size_t)(b * S_ + i) * E_ + h * D_ + d] = f2bf(s);
}

extern "C" void kernel_launch(void* const* d_in, const int* in_sizes, int n_in,
                              void* d_out, int out_size, void* d_ws, size_t ws_size,
                              hipStream_t stream) {
    const float* x   = (const float*)d_in[0];
    const int*   rnd = (const int*)d_in[1];
    const float* qw  = (const float*)d_in[2];
    const float* qb  = (const float*)d_in[3];
    const float* kw  = (const float*)d_in[4];
    const float* kb  = (const float*)d_in[5];
    const float* vw  = (const float*)d_in[6];
    const float* vb  = (const float*)d_in[7];
    const float* ow  = (const float*)d_in[8];
    const float* ob  = (const float*)d_in[9];
    float* out = (float*)d_out;

    char* ws = (char*)d_ws;
    unsigned short* xb    = (unsigned short*)(ws);                       // 8 MB (dead after QKV GEMM)
    unsigned short* wqkv  = (unsigned short*)(ws + 8388608);             // 6 MB
    unsigned short* wo    = (unsigned short*)(ws + 14680064);            // 2 MB
    unsigned short* qkv   = (unsigned short*)(ws + 16777216);            // 24 MB
    unsigned short* attn  = (unsigned short*)(ws + 41943040);            // 8 MB
    float*          gaccp = (float*)(ws);                                // 128 KB (overlaps dead xb)

    const int M = B_ * S_;   // 4096

    {
        int total4 = (M * E_ + 4 * E_ * E_) / 4;
        convert_all<<<total4 / 256, 256, 0, stream>>>(x, qw, kw, vw, ow, xb, wqkv, wo);
    }

    // QKV GEMM: [4096][3072] bf16, BK=64 swizzled, fully-resident grid
    {
        dim3 grid(M / 128, 3 * E_ / 128);
        gemm_qkv<<<grid, 256, 0, stream>>>(xb, wqkv, qb, kb, vb, qkv, M, 3 * E_, E_);
    }

    // global chunks (512) + sparse rows (1024), one dispatch
    attn_fused<<<512 + 1024, 256, 0, stream>>>(qkv, rnd, gaccp, attn);

    // sum global-row partials
    gattn_fin<<<16, 256, 0, stream>>>(gaccp, attn);

    // O GEMM -> fp32 out (BK=64 swizzled)
    {
        dim3 grid(M / 128, E_ / 64);
        gemm_o64<<<grid, 256, 0, stream>>>(attn, wo, ob, out, M, E_, E_);
    }
}

// Round 4
// 167.331 us; speedup vs baseline: 1.1138x; 1.1092x over previous
//
#include <hip/hip_runtime.h>

#define B_  2
#define S_  2048
#define E_  1024
#define H_  16
#define D_  64
#define NGLOB 2
#define NRAND 3
#define WIN 3

typedef __bf16 bf16x8 __attribute__((ext_vector_type(8)));
typedef float  f32x4  __attribute__((ext_vector_type(4)));

__device__ __forceinline__ unsigned short f2bf(float f) {
    unsigned u = __builtin_bit_cast(unsigned, f);
    unsigned r = u + 0x7FFFu + ((u >> 16) & 1u);   // RNE
    return (unsigned short)(r >> 16);
}
__device__ __forceinline__ float bf2f(unsigned short u) {
    return __builtin_bit_cast(float, (unsigned)u << 16);
}

// async global->LDS 16B DMA. LDS dest is wave-uniform base + lane*16.
__device__ __forceinline__ void g2l16(const unsigned short* g, unsigned short* l) {
    __builtin_amdgcn_global_load_lds(
        (const __attribute__((address_space(1))) unsigned*)g,
        (__attribute__((address_space(3))) unsigned*)l, 16, 0, 0);
}

// ---------------- fused fp32 -> bf16 conversion for x + 4 weights ----------------
__global__ __launch_bounds__(256)
void convert_all(const float* __restrict__ x,  const float* __restrict__ qw,
                 const float* __restrict__ kw, const float* __restrict__ vw,
                 const float* __restrict__ ow,
                 unsigned short* __restrict__ xb, unsigned short* __restrict__ wqkv,
                 unsigned short* __restrict__ wo) {
    const int XN = (B_ * S_ * E_) / 4;      // 1048576
    const int WN = (E_ * E_) / 4;           // 262144
    int i = blockIdx.x * blockDim.x + threadIdx.x;
    int r, loc;
    if (i < XN) { r = 0; loc = i; }
    else        { int j = i - XN; r = 1 + (j >> 18); loc = j & (WN - 1); }
    const float* src = r == 0 ? x : r == 1 ? qw : r == 2 ? kw : r == 3 ? vw : ow;
    float4 f = ((const float4*)src)[loc];
    ushort4 u;
    u.x = f2bf(f.x); u.y = f2bf(f.y); u.z = f2bf(f.z); u.w = f2bf(f.w);
    ushort4* dst = r == 0 ? (ushort4*)xb : r == 4 ? (ushort4*)wo
                 : (ushort4*)wqkv + (size_t)(r - 1) * WN;
    dst[loc] = u;
}

// ---------------- QKV GEMM: BK=64, XOR-swizzled LDS (known-good R0 version) -------
__global__ __launch_bounds__(256, 3)
void gemm_qkv(const unsigned short* __restrict__ A,  // [M][K] bf16
              const unsigned short* __restrict__ W,  // [N][K] bf16
              const float* __restrict__ b0, const float* __restrict__ b1,
              const float* __restrict__ b2,
              unsigned short* __restrict__ Cb, int M, int N, int K) {
    __shared__ unsigned short sA[128 * 64];   // 16 KB
    __shared__ unsigned short sB[128 * 64];   // 16 KB
    const int t = threadIdx.x;
    const int lane = t & 63;
    const int wave = t >> 6;
    const int wm = wave >> 1, wn = wave & 1;
    const int lq = lane >> 4;
    const int lr = lane & 15;
    const int bm = blockIdx.x * 128;
    const int bn = blockIdx.y * 128;

    f32x4 acc[4][4] = {};

    for (int k0 = 0; k0 < K; k0 += 64) {
        const unsigned short* Abase = A + (size_t)bm * K + k0;
        const unsigned short* Wbase = W + (size_t)bn * K + k0;
        #pragma unroll
        for (int j = 0; j < 4; ++j) {             // 1024 chunks each
            int c = j * 256 + t;
            int row = c >> 3, cc = c & 7;
            int gcol = ((cc ^ (row & 7)) << 3);   // swizzled source col
            int dst = j * 2048 + wave * 512;      // wave-uniform elem offset
            g2l16(Abase + (size_t)row * K + gcol, sA + dst);
            g2l16(Wbase + (size_t)row * K + gcol, sB + dst);
        }
        __syncthreads();

        #pragma unroll
        for (int ks = 0; ks < 2; ++ks) {
            const int sw = (((ks << 2) + lq) ^ (lr & 7)) << 3;
            bf16x8 af[4], bfr[4];
            #pragma unroll
            for (int i = 0; i < 4; ++i)
                af[i] = *(const bf16x8*)&sA[(wm * 64 + i * 16 + lr) * 64 + sw];
            #pragma unroll
            for (int j = 0; j < 4; ++j)
                bfr[j] = *(const bf16x8*)&sB[(wn * 64 + j * 16 + lr) * 64 + sw];
            #pragma unroll
            for (int i = 0; i < 4; ++i)
                #pragma unroll
                for (int j = 0; j < 4; ++j)
                    acc[i][j] = __builtin_amdgcn_mfma_f32_16x16x32_bf16(af[i], bfr[j], acc[i][j], 0, 0, 0);
        }
        __syncthreads();
    }

    #pragma unroll
    for (int i = 0; i < 4; ++i) {
        int row0 = bm + wm * 64 + i * 16 + lq * 4;
        #pragma unroll
        for (int j = 0; j < 4; ++j) {
            int col = bn + wn * 64 + j * 16 + lr;
            const float* bp = col < E_ ? b0 : (col < 2 * E_ ? b1 : b2);
            float bv = bp[col & (E_ - 1)];
            #pragma unroll
            for (int r = 0; r < 4; ++r)
                Cb[(size_t)(row0 + r) * N + col] = f2bf(acc[i][j][r] + bv);
        }
    }
}

// ---------------- O GEMM: 128x64 tile, BK=64 XOR-swizzled ----------------
__global__ __launch_bounds__(256, 2)
void gemm_o64(const unsigned short* __restrict__ A,
              const unsigned short* __restrict__ W,
              const float* __restrict__ bias,
              float* __restrict__ Cf, int M, int N, int K) {
    __shared__ unsigned short sA[128 * 64];   // 16 KB
    __shared__ unsigned short sB[64 * 64];    // 8 KB
    const int t = threadIdx.x;
    const int lane = t & 63;
    const int wave = t >> 6;
    const int lq = lane >> 4;
    const int lr = lane & 15;
    const int bm = blockIdx.x * 128;
    const int bn = blockIdx.y * 64;

    f32x4 acc[2][4] = {};

    for (int k0 = 0; k0 < K; k0 += 64) {
        const unsigned short* Abase = A + (size_t)bm * K + k0;
        const unsigned short* Wbase = W + (size_t)bn * K + k0;
        #pragma unroll
        for (int j = 0; j < 4; ++j) {           // A: 1024 chunks
            int c = j * 256 + t;
            int row = c >> 3, cc = c & 7;
            int gcol = ((cc ^ (row & 7)) << 3);
            int dst = j * 2048 + wave * 512;
            g2l16(Abase + (size_t)row * K + gcol, sA + dst);
        }
        #pragma unroll
        for (int j = 0; j < 2; ++j) {           // B: 512 chunks
            int c = j * 256 + t;
            int row = c >> 3, cc = c & 7;
            int gcol = ((cc ^ (row & 7)) << 3);
            int dst = j * 2048 + wave * 512;
            g2l16(Wbase + (size_t)row * K + gcol, sB + dst);
        }
        __syncthreads();

        #pragma unroll
        for (int ks = 0; ks < 2; ++ks) {
            const int sw = (((ks << 2) + lq) ^ (lr & 7)) << 3;
            bf16x8 af[2], bfr[4];
            #pragma unroll
            for (int i = 0; i < 2; ++i)
                af[i] = *(const bf16x8*)&sA[(wave * 32 + i * 16 + lr) * 64 + sw];
            #pragma unroll
            for (int j = 0; j < 4; ++j)
                bfr[j] = *(const bf16x8*)&sB[(j * 16 + lr) * 64 + sw];
            #pragma unroll
            for (int i = 0; i < 2; ++i)
                #pragma unroll
                for (int j = 0; j < 4; ++j)
                    acc[i][j] = __builtin_amdgcn_mfma_f32_16x16x32_bf16(af[i], bfr[j], acc[i][j], 0, 0, 0);
        }
        __syncthreads();
    }

    #pragma unroll
    for (int i = 0; i < 2; ++i) {
        int row0 = bm + wave * 32 + i * 16 + lq * 4;
        #pragma unroll
        for (int j = 0; j < 4; ++j) {
            int col = bn + j * 16 + lr;
            float bv = bias[col];
            #pragma unroll
            for (int r = 0; r < 4; ++r)
                Cf[(size_t)(row0 + r) * N + col] = acc[i][j][r] + bv;
        }
    }
}

// ---------------- fused: flash-style global chunks + sparse rows -----------------
// R4: blocks [0,512) = (tuple x 256-key chunk). NO score recompute (R2/R3's 52us
// tail was the full-2048 score loop with 64-rows-per-load-instr uncoalesced reads).
// Wave covers 8 keys x 8 chunk-lanes: each K load instr = 8 rows x 128B contiguous
// (100% line use), dot finished by 3-level shfl_xor in the 8-lane group.
// Chunk-local softmax partials (m_c, sum_c) + UNNORMALIZED PV partial -> scratch;
// gattn_fin merges with e^(m_c-M) rescale. Blocks [512,1536) = sparse (unchanged).
__global__ __launch_bounds__(256)
void attn_fused(const unsigned short* __restrict__ qkv,
                const int* __restrict__ rnd,
                float* __restrict__ gaccp, float* __restrict__ gms,
                unsigned short* __restrict__ attn) {
    const int NB = B_ * (S_ - 2);     // 4092
    int t = threadIdx.x;

    if (blockIdx.x < 512) {
        // ---- one (tuple, key-chunk) per block ----
        int tup = blockIdx.x >> 3, seg = blockIdx.x & 7;
        int b = tup >> 5, i = (tup >> 4) & 1, h = tup & 15;
        int w = t >> 6, l = t & 63;
        __shared__ float ps[256];
        __shared__ float red[4];
        __shared__ float ov[4][D_];

        // q chunk for this lane: 8 bf16 at chunk (l&7) of head slice
        const bf16x8* qp = (const bf16x8*)(qkv + (size_t)(b * S_ + i) * 3072 + h * D_);
        bf16x8 qv = qp[l & 7];
        float qreg[8];
        #pragma unroll
        for (int j = 0; j < 8; ++j) qreg[j] = (float)qv[j];

        // scores: wave w covers keys [seg*256 + w*64, +64), 8 keys/iter
        const int key0 = seg * 256 + w * 64;
        float sc[8];
        #pragma unroll
        for (int it = 0; it < 8; ++it) {
            int key = key0 + it * 8 + (l >> 3);
            const bf16x8* kp = (const bf16x8*)(qkv + (size_t)(b * S_ + key) * 3072 + E_ + h * D_);
            bf16x8 kv = kp[l & 7];
            float s = 0.f;
            #pragma unroll
            for (int j = 0; j < 8; ++j) s += qreg[j] * (float)kv[j];
            s += __shfl_xor(s, 1);
            s += __shfl_xor(s, 2);
            s += __shfl_xor(s, 4);
            sc[it] = s * 0.125f;
        }
        #pragma unroll
        for (int it = 0; it < 8; ++it)
            if ((l & 7) == 0) ps[w * 64 + it * 8 + (l >> 3)] = sc[it];
        __syncthreads();

        // chunk-local softmax partials
        float v = ps[t];
        float m = v;
        #pragma unroll
        for (int o = 32; o; o >>= 1) m = fmaxf(m, __shfl_xor(m, o));
        if (l == 0) red[w] = m;
        __syncthreads();
        m = fmaxf(fmaxf(red[0], red[1]), fmaxf(red[2], red[3]));
        float e = __expf(v - m);
        float sum = e;
        #pragma unroll
        for (int o = 32; o; o >>= 1) sum += __shfl_xor(sum, o);
        __syncthreads();
        if (l == 0) red[w] = sum;
        ps[t] = e;                       // unnormalized probs
        __syncthreads();
        if (t == 0) {
            float stot = red[0] + red[1] + red[2] + red[3];
            gms[(tup * 8 + seg) * 2]     = m;
            gms[(tup * 8 + seg) * 2 + 1] = stot;
        }

        // PV over this chunk: wave w keys [key0, +64), lane l = dim
        const unsigned short* vbase =
            qkv + (size_t)(b * S_ + key0) * 3072 + 2 * E_ + h * D_ + l;
        const float* pw = ps + w * 64;
        float acc = 0.f;
        #pragma unroll 8
        for (int k = 0; k < 64; ++k)
            acc += pw[k] * bf2f(vbase[(size_t)k * 3072]);
        ov[w][l] = acc;
        __syncthreads();
        if (w == 0)
            gaccp[((size_t)tup * 8 + seg) * D_ + l] =
                ov[0][l] + ov[1][l] + ov[2][l] + ov[3][l];
        return;
    }

    // ---- sparse rows: one wave per row ----
    int bb = blockIdx.x - 512;                        // [0,1024)
    int bidx = (bb & 7) * 128 + (bb >> 3);            // XCD swizzle
    int w = t >> 6, l = t & 63;
    int row = bidx * 4 + w;
    bool valid = row < NB;
    int b = row / (S_ - 2);
    int i = row % (S_ - 2) + 2;
    if (!valid) { b = 0; i = 2; }

    __shared__ int   cols_s[4][12];
    __shared__ int   ncol_sh[4];
    __shared__ float pr_s[4][16 * 13 + 3];

    const bf16x8* qp = (const bf16x8*)(qkv + (size_t)(b * S_ + i) * 3072);
    bf16x8 q0 = qp[l * 2], q1 = qp[l * 2 + 1];
    float qreg[16];
    #pragma unroll
    for (int j = 0; j < 8; ++j) { qreg[j] = (float)q0[j]; qreg[8 + j] = (float)q1[j]; }

    if (l == 0) {
        int* cols = cols_s[w];
        int n = 0;
        cols[n++] = 0; cols[n++] = 1;
        int lo = i - WIN; if (lo < NGLOB) lo = NGLOB;
        int hi = i + WIN; if (hi > S_ - 1) hi = S_ - 1;
        for (int j = lo; j <= hi; ++j) cols[n++] = j;
        for (int r = 0; r < NRAND; ++r) {
            int c = rnd[i * NRAND + r];
            bool dup = false;
            for (int q = 0; q < n; ++q) dup = dup || (cols[q] == c);
            if (!dup) cols[n++] = c;
        }
        ncol_sh[w] = n;
        for (int q = n; q < 12; ++q) cols[q] = 0;
    }
    __syncthreads();
    const int n = ncol_sh[w];
    const int h4 = l >> 2;

    float sco[12];
    #pragma unroll
    for (int c = 0; c < 12; ++c) {
        const bf16x8* kp = (const bf16x8*)(qkv + (size_t)(b * S_ + cols_s[w][c]) * 3072 + E_);
        bf16x8 k0 = kp[l * 2], k1 = kp[l * 2 + 1];
        float s = 0.f;
        #pragma unroll
        for (int j = 0; j < 8; ++j) s += qreg[j] * (float)k0[j] + qreg[8 + j] * (float)k1[j];
        s += __shfl_xor(s, 1);
        s += __shfl_xor(s, 2);
        sco[c] = (c < n) ? s * 0.125f : -1e30f;
    }

    if ((l & 3) == 0) {
        float m = -1e30f;
        #pragma unroll
        for (int c = 0; c < 12; ++c) m = fmaxf(m, sco[c]);
        float sum = 0.f;
        #pragma unroll
        for (int c = 0; c < 12; ++c) { float e = __expf(sco[c] - m); sco[c] = e; sum += e; }
        float inv = 1.f / sum;
        #pragma unroll
        for (int c = 0; c < 12; ++c) pr_s[w][h4 * 13 + c] = sco[c] * inv;
    }
    __syncthreads();

    float o[16] = {};
    #pragma unroll
    for (int c = 0; c < 12; ++c) {
        float p = pr_s[w][h4 * 13 + c];
        const bf16x8* vp = (const bf16x8*)(qkv + (size_t)(b * S_ + cols_s[w][c]) * 3072 + 2 * E_);
        bf16x8 v0 = vp[l * 2], v1 = vp[l * 2 + 1];
        #pragma unroll
        for (int j = 0; j < 8; ++j) { o[j] += p * (float)v0[j]; o[8 + j] += p * (float)v1[j]; }
    }

    if (valid) {
        ushort4 u0, u1, u2, u3;
        u0.x = f2bf(o[0]);  u0.y = f2bf(o[1]);  u0.z = f2bf(o[2]);  u0.w = f2bf(o[3]);
        u1.x = f2bf(o[4]);  u1.y = f2bf(o[5]);  u1.z = f2bf(o[6]);  u1.w = f2bf(o[7]);
        u2.x = f2bf(o[8]);  u2.y = f2bf(o[9]);  u2.z = f2bf(o[10]); u2.w = f2bf(o[11]);
        u3.x = f2bf(o[12]); u3.y = f2bf(o[13]); u3.z = f2bf(o[14]); u3.w = f2bf(o[15]);
        ushort4* op = (ushort4*)(attn + (size_t)(b * S_ + i) * E_ + l * 16);
        op[0] = u0; op[1] = u1; op[2] = u2; op[3] = u3;
    }
}

// merge 8 chunk partials per tuple: out = sum_c o_c * e^(m_c-M) / sum_c s_c * e^(m_c-M)
__global__ __launch_bounds__(256)
void gattn_fin(const float* __restrict__ gaccp, const float* __restrict__ gms,
               unsigned short* __restrict__ attn) {
    int gid = blockIdx.x * 256 + threadIdx.x;   // 4096
    int tup = gid >> 6, d = gid & 63;
    int b = tup >> 5, i = (tup >> 4) & 1, h = tup & 15;
    float mc[8], sc[8], M = -1e30f;
    #pragma unroll
    for (int c = 0; c < 8; ++c) {
        mc[c] = gms[(tup * 8 + c) * 2];
        sc[c] = gms[(tup * 8 + c) * 2 + 1];
        M = fmaxf(M, mc[c]);
    }
    float den = 0.f, num = 0.f;
    #pragma unroll
    for (int c = 0; c < 8; ++c) {
        float f = __expf(mc[c] - M);
        den += sc[c] * f;
        num += gaccp[((size_t)tup * 8 + c) * D_ + d] * f;
    }
    attn[(size_t)(b * S_ + i) * E_ + h * D_ + d] = f2bf(num / den);
}

extern "C" void kernel_launch(void* const* d_in, const int* in_sizes, int n_in,
                              void* d_out, int out_size, void* d_ws, size_t ws_size,
                              hipStream_t stream) {
    const float* x   = (const float*)d_in[0];
    const int*   rnd = (const int*)d_in[1];
    const float* qw  = (const float*)d_in[2];
    const float* qb  = (const float*)d_in[3];
    const float* kw  = (const float*)d_in[4];
    const float* kb  = (const float*)d_in[5];
    const float* vw  = (const float*)d_in[6];
    const float* vb  = (const float*)d_in[7];
    const float* ow  = (const float*)d_in[8];
    const float* ob  = (const float*)d_in[9];
    float* out = (float*)d_out;

    char* ws = (char*)d_ws;
    unsigned short* xb    = (unsigned short*)(ws);                       // 8 MB (dead after QKV GEMM)
    unsigned short* wqkv  = (unsigned short*)(ws + 8388608);             // 6 MB
    unsigned short* wo    = (unsigned short*)(ws + 14680064);            // 2 MB
    unsigned short* qkv   = (unsigned short*)(ws + 16777216);            // 24 MB
    unsigned short* attn  = (unsigned short*)(ws + 41943040);            // 8 MB
    float*          gaccp = (float*)(ws);                                // 128 KB (overlaps dead xb)
    float*          gms   = (float*)(ws + 131072);                       // 4 KB

    const int M = B_ * S_;   // 4096

    {
        int total4 = (M * E_ + 4 * E_ * E_) / 4;
        convert_all<<<total4 / 256, 256, 0, stream>>>(x, qw, kw, vw, ow, xb, wqkv, wo);
    }

    // QKV GEMM: [4096][3072] bf16, BK=64 swizzled, fully-resident grid
    {
        dim3 grid(M / 128, 3 * E_ / 128);
        gemm_qkv<<<grid, 256, 0, stream>>>(xb, wqkv, qb, kb, vb, qkv, M, 3 * E_, E_);
    }

    // global chunks (512, flash-partial) + sparse rows (1024), one dispatch
    attn_fused<<<512 + 1024, 256, 0, stream>>>(qkv, rnd, gaccp, gms, attn);

    // merge global-row partials
    gattn_fin<<<16, 256, 0, stream>>>(gaccp, gms, attn);

    // O GEMM -> fp32 out (BK=64 swizzled)
    {
        dim3 grid(M / 128, E_ / 64);
        gemm_o64<<<grid, 256, 0, stream>>>(attn, wo, ob, out, M, E_, E_);
    }
}